// Round 11
// baseline (359.019 us; speedup 1.0000x reference)
//
#include <hip/hip_runtime.h>
#include <math.h>

#define BG   256                   // graphs
#define NN   512                   // nodes per graph
#define EPG  (NN * 16)             // 8192 edges per graph
#define NE   (BG * EPG)            // 2097152 edges

__device__ __forceinline__ float4 f4fma(float s, float4 a, float4 c) {
    c.x = fmaf(s, a.x, c.x); c.y = fmaf(s, a.y, c.y);
    c.z = fmaf(s, a.z, c.z); c.w = fmaf(s, a.w, c.w);
    return c;
}

// one 64x64 GEMM tile, r16-verbatim FMA order. W from global (L1-resident).
__device__ __forceinline__ void gemm_tile(const float* __restrict__ shx,
                                          const float4* __restrict__ W4,
                                          int row0, int rg, int cg, float4 a[4]) {
    float4 acc0 = make_float4(0.f, 0.f, 0.f, 0.f);
    float4 acc1 = acc0, acc2 = acc0, acc3 = acc0;
#pragma unroll
    for (int k4 = 0; k4 < 16; ++k4) {
        float4 xv0 = *(const float4*)&shx[(row0 + rg * 4 + 0) * 68 + k4 * 4];
        float4 xv1 = *(const float4*)&shx[(row0 + rg * 4 + 1) * 68 + k4 * 4];
        float4 xv2 = *(const float4*)&shx[(row0 + rg * 4 + 2) * 68 + k4 * 4];
        float4 xv3 = *(const float4*)&shx[(row0 + rg * 4 + 3) * 68 + k4 * 4];
        float4 wv0 = W4[(k4 * 4 + 0) * 16 + cg];
        float4 wv1 = W4[(k4 * 4 + 1) * 16 + cg];
        float4 wv2 = W4[(k4 * 4 + 2) * 16 + cg];
        float4 wv3 = W4[(k4 * 4 + 3) * 16 + cg];
        acc0 = f4fma(xv0.x, wv0, acc0); acc0 = f4fma(xv0.y, wv1, acc0);
        acc0 = f4fma(xv0.z, wv2, acc0); acc0 = f4fma(xv0.w, wv3, acc0);
        acc1 = f4fma(xv1.x, wv0, acc1); acc1 = f4fma(xv1.y, wv1, acc1);
        acc1 = f4fma(xv1.z, wv2, acc1); acc1 = f4fma(xv1.w, wv3, acc1);
        acc2 = f4fma(xv2.x, wv0, acc2); acc2 = f4fma(xv2.y, wv1, acc2);
        acc2 = f4fma(xv2.z, wv2, acc2); acc2 = f4fma(xv2.w, wv3, acc2);
        acc3 = f4fma(xv3.x, wv0, acc3); acc3 = f4fma(xv3.y, wv1, acc3);
        acc3 = f4fma(xv3.z, wv2, acc3); acc3 = f4fma(xv3.w, wv3, acc3);
    }
    a[0] = acc0; a[1] = acc1; a[2] = acc2; a[3] = acc3;
}

// ---- r22: r21 + barrier-free GEMM writeback. ----
// h = x@W is ROW-LOCAL: output row r reads only input row r. Wave w's lanes
// own 16 rows exclusively (4 rg-groups of 4 rows); reads of those rows are
// wave-internal and precede the writes in program order (LDS in-order per
// wave) -> in-place overwrite needs NO barrier. Removes the 32-VGPR acc
// live range across __syncthreads (the remaining ~23MB scratch spill) and
// one barrier per GEMM. FMA order per element unchanged -> bitwise id.
// Everything else r21-verbatim (2-pass CSR, LDS pairs2, block-local stage2).
__global__ __launch_bounds__(1024)
void mega_kernel(const int* __restrict__ esrc, const int* __restrict__ edst,
                 const float* __restrict__ eatt, int2* __restrict__ pairs,
                 const float4* __restrict__ X4,
                 const float4* __restrict__ W1_4, const float4* __restrict__ b1_4,
                 const float4* __restrict__ wp1_4, const float* __restrict__ bp1,
                 const float4* __restrict__ W2_4, const float4* __restrict__ b2_4,
                 const float4* __restrict__ wp2_4, const float* __restrict__ bp2,
                 float* __restrict__ out) {
    __shared__ __align__(16) float smem[40720];
    float* shx  = smem;                           // [512*68]
    float* S    = smem + 34816;
    int*   cnt   = (int*)S;                       // [512]
    int*   rstl  = (int*)S + 512;                 // [512]
    float* sdinv = S + 1024;                      // [512]
    int*   perm  = (int*)S + 1536;                // [512] (alias: nor)
    int*   scn   = (int*)S + 2048;                // [512] (alias: shp)
    float* shp   = S + 2048;
    float* wsum  = S + 2560;                      // [512] (alias: ssc)
    float* ssc   = S + 2560;
    int*   rnk   = (int*)S + 3072;                // [512]
    float* sbw   = S + 3584;                      // [64]
    int*   hist  = (int*)S + 3648;                // [64]
    int*   wtot  = (int*)S + 3712;                // [16]
    float* x1rs  = S + 3728;                      // [128]
    float4* redx = (float4*)(S + 3856);           // [512 f4] readout scratch
    float* wsum2 = S + 3856;                      // [256] stage2 (redx dead then)
    int2*  lp    = (int2*)&shx[256 * 68];         // [8192] stage2 pairs overlay

    int g = blockIdx.x, nb1 = g * NN, e0 = g * EPG;
    int t = threadIdx.x;
    int lane16 = t & 15, lane = t & 63;

    const int4*   edst4 = (const int4*)(edst + e0);
    const int4*   esrc4 = (const int4*)(esrc + e0);
    const float4* eatt4 = (const float4*)(eatt + e0);

    // ================= STAGE 1 =================
    // ---- CSR1, 2-pass; lp1 = 8192 int2 over free shx ----
    for (int i = t; i < NN; i += 1024) { cnt[i] = 0; wsum[i] = 0.f; }
    __syncthreads();
    {   // pass A: count (no esrc needed; regs die here)
        int ed[8]; float ea[8];
#pragma unroll
        for (int c = 0; c < 2; ++c) {
            int ch = t + c * 1024;
            int4 dd = edst4[ch]; float4 ww = eatt4[ch];
            ed[c*4+0]=dd.x; ed[c*4+1]=dd.y; ed[c*4+2]=dd.z; ed[c*4+3]=dd.w;
            ea[c*4+0]=ww.x; ea[c*4+1]=ww.y; ea[c*4+2]=ww.z; ea[c*4+3]=ww.w;
        }
#pragma unroll
        for (int j = 0; j < 8; ++j) {
            int dl = ed[j] - nb1;
            atomicAdd(&cnt[dl], 1);
            atomicAdd(&wsum[dl], ea[j]);
        }
    }
    __syncthreads();
    {   // scan (r18-verbatim)
        int wv = t >> 6;
        int xval = (t < NN) ? cnt[t] : 0;
        int xs = xval;
#pragma unroll
        for (int off = 1; off < 64; off <<= 1) {
            int v = __shfl_up(xs, off, 64);
            if (lane >= off) xs += v;
        }
        if (lane == 63) wtot[wv] = xs;
        __syncthreads();
        int woff = 0;
#pragma unroll
        for (int w = 0; w < 16; ++w) { int wt = wtot[w]; if (w < wv) woff += wt; }
        xs += woff;
        if (t < NN) {
            int st = xs - xval;
            rstl[t] = st;
            sdinv[t] = rsqrtf(wsum[t] + 1.0f);
            scn[t] = st;
        }
    }
    __syncthreads();
    {   // pass B: reload edges, cf, scatter into lp1 (full 8192)
        int2* lp1 = (int2*)smem;
        int ed[8], es[8]; float ea[8];
#pragma unroll
        for (int c = 0; c < 2; ++c) {
            int ch = t + c * 1024;
            int4 dd = edst4[ch]; int4 ss = esrc4[ch]; float4 ww = eatt4[ch];
            ed[c*4+0]=dd.x; ed[c*4+1]=dd.y; ed[c*4+2]=dd.z; ed[c*4+3]=dd.w;
            es[c*4+0]=ss.x; es[c*4+1]=ss.y; es[c*4+2]=ss.z; es[c*4+3]=ss.w;
            ea[c*4+0]=ww.x; ea[c*4+1]=ww.y; ea[c*4+2]=ww.z; ea[c*4+3]=ww.w;
        }
#pragma unroll
        for (int j = 0; j < 8; ++j) {
            int dl = ed[j] - nb1, sl = es[j] - nb1;
            float cf = sdinv[dl] * ea[j] * sdinv[sl];
            int slot = atomicAdd(&scn[dl], 1);
            lp1[slot] = make_int2(sl, __float_as_int(cf));
        }
        __syncthreads();
        for (int k = t; k < EPG; k += 1024) pairs[e0 + k] = lp1[k];
    }
    __syncthreads();
    // ---- stage x + inits ----
    for (int i = t; i < NN * 16; i += 1024) {
        int r = i >> 4, c4 = i & 15;
        *(float4*)&shx[r * 68 + c4 * 4] = X4[(size_t)nb1 * 16 + i];
    }
    if (t < 64) { sbw[t] = ((const float*)b1_4)[t]; hist[t] = 0; }
    for (int i = t; i < NN; i += 1024) rnk[i] = 0;
    __syncthreads();
    // ---- GEMM1 (8 tiles; per-tile compute+write, wave-exclusive rows) ----
    {
        int q = t >> 8, tq = t & 255, rg = tq >> 4, cg = tq & 15;
#pragma unroll
        for (int tt = 0; tt < 2; ++tt) {
            int row0 = (tt * 4 + q) * 64;
            float4 a4[4];
            gemm_tile(shx, W1_4, row0, rg, cg, a4);
            *(float4*)&shx[(row0 + rg * 4 + 0) * 68 + cg * 4] = a4[0];
            *(float4*)&shx[(row0 + rg * 4 + 1) * 68 + cg * 4] = a4[1];
            *(float4*)&shx[(row0 + rg * 4 + 2) * 68 + cg * 4] = a4[2];
            *(float4*)&shx[(row0 + rg * 4 + 3) * 68 + cg * 4] = a4[3];
        }
    }
    __syncthreads();
    // ---- tail1: hist/perm ----
    for (int i = t; i < NN; i += 1024) atomicAdd(&hist[min(cnt[i], 63)], 1);
    __syncthreads();
    if (t < 64) {
        int v = hist[t], s = v;
#pragma unroll
        for (int off = 1; off < 64; off <<= 1) {
            int u = __shfl_up(s, off, 64);
            if (lane >= off) s += u;
        }
        hist[t] = s - v;
    }
    __syncthreads();
    for (int i = t; i < NN; i += 1024) {
        int pos = atomicAdd(&hist[min(cnt[i], 63)], 1);
        perm[pos] = i;
    }
    __syncthreads();
    // ---- conv1 (LPN=2, QF=8, depth-2 prefetch, global pairs) ----
    {
        int idx2 = t >> 1, half = t & 1, fb = half * 8;
        int nl = perm[idx2];
        int st = rstl[nl], cn = cnt[nl];
        float di = sdinv[nl], dii = di * di;
        const int2* pb = pairs + e0 + st;
        float4 acc[8];
#pragma unroll
        for (int c = 0; c < 8; ++c) {
            float4 xv = *(const float4*)&shx[nl * 68 + (fb + c) * 4];
            acc[c].x = fmaf(xv.x, dii, sbw[(fb + c) * 4 + 0]);
            acc[c].y = fmaf(xv.y, dii, sbw[(fb + c) * 4 + 1]);
            acc[c].z = fmaf(xv.z, dii, sbw[(fb + c) * 4 + 2]);
            acc[c].w = fmaf(xv.w, dii, sbw[(fb + c) * 4 + 3]);
        }
        int2 p0 = (cn > 0) ? pb[0] : make_int2(0, 0);
        int2 p1 = (cn > 1) ? pb[1] : make_int2(0, 0);
        for (int j = 0; j < cn; ++j) {
            int2 p2 = (j + 2 < cn) ? pb[j + 2] : make_int2(0, 0);
            float cfv = __int_as_float(p0.y);
            int   s   = p0.x;
#pragma unroll
            for (int c = 0; c < 8; ++c)
                acc[c] = f4fma(cfv, *(const float4*)&shx[s * 68 + (fb + c) * 4], acc[c]);
            p0 = p1; p1 = p2;
        }
#pragma unroll
        for (int c = 0; c < 8; ++c) {
            acc[c].x = fmaxf(acc[c].x, 0.f); acc[c].y = fmaxf(acc[c].y, 0.f);
            acc[c].z = fmaxf(acc[c].z, 0.f); acc[c].w = fmaxf(acc[c].w, 0.f);
        }
        __syncthreads();
#pragma unroll
        for (int c = 0; c < 8; ++c)
            *(float4*)&shx[nl * 68 + (fb + c) * 4] = acc[c];
    }
    __syncthreads();
    // ---- hp1 ----
    if (t < 512) {
        int wv8 = t >> 6, sub4 = (t >> 4) & 3;
        float4 w4 = wp1_4[lane16];
#pragma unroll
        for (int p = 0; p < 16; ++p) {
            int n2 = p * 32 + wv8 * 4 + sub4;
            float4 a = *(const float4*)&shx[n2 * 68 + lane16 * 4];
            float tt = a.x * w4.x + a.y * w4.y + a.z * w4.z + a.w * w4.w;
            tt += __shfl_xor(tt, 1, 64); tt += __shfl_xor(tt, 2, 64);
            tt += __shfl_xor(tt, 4, 64); tt += __shfl_xor(tt, 8, 64);
            if (lane16 == 0) shp[n2] = tt;
        }
    }
    __syncthreads();
    // ---- score1 ----
    if (t < NN) {
        int i = perm[t];
        int st = rstl[i], cn = cnt[i];
        float di = sdinv[i];
        const int2* pb = pairs + e0 + st;
        float a = fmaf(shp[i], di * di, bp1[0]);
        int2 q0 = (cn > 0) ? pb[0] : make_int2(0, 0);
        int2 q1 = (cn > 1) ? pb[1] : make_int2(0, 0);
        for (int j = 0; j < cn; ++j) {
            int2 q2v = (j + 2 < cn) ? pb[j + 2] : make_int2(0, 0);
            a = fmaf(__int_as_float(q0.y), shp[q0.x], a);
            q0 = q1; q1 = q2v;
        }
        ssc[i] = a;
    }
    __syncthreads();
    // ---- rank1 (2 partials per node) ----
    {
        int part = t >> 9, i = t & 511;
        float si = ssc[i];
        int j0 = part * 256, rank = 0;
        for (int j = j0; j < j0 + 256; j += 4) {
            float4 sj = *(const float4*)&ssc[j];
            rank += (sj.x > si) || (sj.x == si && j     < i);
            rank += (sj.y > si) || (sj.y == si && j + 1 < i);
            rank += (sj.z > si) || (sj.z == si && j + 2 < i);
            rank += (sj.w > si) || (sj.w == si && j + 3 < i);
        }
        atomicAdd(&rnk[i], rank);
    }
    __syncthreads();
    // ---- readout1 -> x1rs (2-pass 8KB reduce) ----
    {
        float4 mx = make_float4(-3.402823466e38f, -3.402823466e38f, -3.402823466e38f, -3.402823466e38f);
        float4 sm = make_float4(0.f, 0.f, 0.f, 0.f);
        if (t < 512) {
            int wv8 = t >> 6, sub4 = (t >> 4) & 3;
#pragma unroll
            for (int p = 0; p < 16; ++p) {
                int n2 = p * 32 + wv8 * 4 + sub4;
                int r = rnk[n2];
                if (r < 256) {
                    float gt = tanhf(ssc[n2]);
                    float4 v = *(const float4*)&shx[n2 * 68 + lane16 * 4];
                    v.x *= gt; v.y *= gt; v.z *= gt; v.w *= gt;
                    mx.x = fmaxf(mx.x, v.x); mx.y = fmaxf(mx.y, v.y);
                    mx.z = fmaxf(mx.z, v.z); mx.w = fmaxf(mx.w, v.w);
                    sm.x += v.x; sm.y += v.y; sm.z += v.z; sm.w += v.w;
                }
            }
        }
        int grp = t >> 4;
        __syncthreads();
        if (t < 512) redx[grp * 16 + lane16] = mx;
        __syncthreads();
        float mr[4] = {0, 0, 0, 0};
        if (grp == 0) {
#pragma unroll
            for (int u = 1; u < 32; ++u) {
                float4 a = redx[u * 16 + lane16];
                mx.x = fmaxf(mx.x, a.x); mx.y = fmaxf(mx.y, a.y);
                mx.z = fmaxf(mx.z, a.z); mx.w = fmaxf(mx.w, a.w);
            }
            mr[0] = mx.x; mr[1] = mx.y; mr[2] = mx.z; mr[3] = mx.w;
        }
        __syncthreads();
        if (t < 512) redx[grp * 16 + lane16] = sm;
        __syncthreads();
        if (grp == 0) {
#pragma unroll
            for (int u = 1; u < 32; ++u) {
                float4 b = redx[u * 16 + lane16];
                sm.x += b.x; sm.y += b.y; sm.z += b.z; sm.w += b.w;
            }
            float invK = 1.f / 256.f;
            int c = lane16 * 4;
            float ar[4] = {sm.x * invK, sm.y * invK, sm.z * invK, sm.w * invK};
#pragma unroll
            for (int u = 0; u < 4; ++u) {
                x1rs[c + u]      = mr[u];
                x1rs[64 + c + u] = ar[u];
            }
        }
    }
    // ---- compact: gated selected rows -> shx rows 0..255 ----
    {
        int* nor = perm;                         // perm dead after score1
        __syncthreads();
        for (int i = t; i < NN; i += 1024) {
            int r = rnk[i];
            if (r < 256) nor[r] = i;
        }
        __syncthreads();
        float4 stash[4];
        int rr[4], cc[4];
#pragma unroll
        for (int u = 0; u < 4; ++u) {
            int idx = t + u * 1024;
            rr[u] = idx >> 4; cc[u] = idx & 15;
            int n = nor[rr[u]];
            float gt = tanhf(ssc[n]);
            float4 v = *(const float4*)&shx[n * 68 + cc[u] * 4];
            v.x *= gt; v.y *= gt; v.z *= gt; v.w *= gt;
            stash[u] = v;
        }
        __syncthreads();                          // all reads of h complete
#pragma unroll
        for (int u = 0; u < 4; ++u)
            *(float4*)&shx[rr[u] * 68 + cc[u] * 4] = stash[u];
        __syncthreads();
    }

    // ================= STAGE 2 (xn in shx rows 0..255) =================
    // ---- CSR2, 2-pass (remap via stage1 rnk still in LDS) ----
    for (int i = t; i < 256; i += 1024) { cnt[i] = 0; wsum2[i] = 0.f; }
    __syncthreads();
    {   // pass A: load + remap + count (regs die here)
        int ed[8], es[8]; float ea[8];
#pragma unroll
        for (int c = 0; c < 2; ++c) {
            int ch = t + c * 1024;
            int4 dd = edst4[ch]; int4 ss = esrc4[ch]; float4 ww = eatt4[ch];
            ed[c*4+0]=dd.x; ed[c*4+1]=dd.y; ed[c*4+2]=dd.z; ed[c*4+3]=dd.w;
            es[c*4+0]=ss.x; es[c*4+1]=ss.y; es[c*4+2]=ss.z; es[c*4+3]=ss.w;
            ea[c*4+0]=ww.x; ea[c*4+1]=ww.y; ea[c*4+2]=ww.z; ea[c*4+3]=ww.w;
        }
#pragma unroll
        for (int j = 0; j < 8; ++j) {
            int rd = rnk[ed[j] - nb1], rs = rnk[es[j] - nb1];
            if (rd < 256 && rs < 256) {
                atomicAdd(&cnt[rd], 1);
                atomicAdd(&wsum2[rd], ea[j]);
            }
        }
    }
    __syncthreads();
    {   // scan2
        int wv = t >> 6;
        int xval = 0, xs = 0;
        if (t < 256) {
            xval = cnt[t];
            xs = xval;
#pragma unroll
            for (int off = 1; off < 64; off <<= 1) {
                int v = __shfl_up(xs, off, 64);
                if (lane >= off) xs += v;
            }
            if (lane == 63) wtot[wv] = xs;
        }
        __syncthreads();
        if (t < 256) {
            int woff = 0;
#pragma unroll
            for (int w = 0; w < 4; ++w) { int wt = wtot[w]; if (w < wv) woff += wt; }
            xs += woff;
            int st = xs - xval;
            rstl[t] = st;
            sdinv[t] = rsqrtf(wsum2[t] + 1.0f);
            scn[t] = st;
        }
    }
    __syncthreads();
    {   // pass B: reload + remap + cf + scatter into lp (LDS) — rnk NOT yet zeroed
        int ed[8], es[8]; float ea[8];
#pragma unroll
        for (int c = 0; c < 2; ++c) {
            int ch = t + c * 1024;
            int4 dd = edst4[ch]; int4 ss = esrc4[ch]; float4 ww = eatt4[ch];
            ed[c*4+0]=dd.x; ed[c*4+1]=dd.y; ed[c*4+2]=dd.z; ed[c*4+3]=dd.w;
            es[c*4+0]=ss.x; es[c*4+1]=ss.y; es[c*4+2]=ss.z; es[c*4+3]=ss.w;
            ea[c*4+0]=ww.x; ea[c*4+1]=ww.y; ea[c*4+2]=ww.z; ea[c*4+3]=ww.w;
        }
#pragma unroll
        for (int j = 0; j < 8; ++j) {
            int rd = rnk[ed[j] - nb1], rs = rnk[es[j] - nb1];
            if (rd < 256 && rs < 256) {
                float cf = sdinv[rd] * ea[j] * sdinv[rs];
                int slot = atomicAdd(&scn[rd], 1);
                lp[slot] = make_int2(rs, __float_as_int(cf));
            }
        }
    }
    __syncthreads();
    // stage2 inits (after pass B: rnk reads complete)
    if (t < 256) rnk[t] = 0;
    if (t < 64) { sbw[t] = ((const float*)b2_4)[t]; hist[t] = 0; }
    __syncthreads();
    // ---- GEMM2 (4 tiles; compute+write, wave-exclusive rows, no barrier) ----
    {
        int q = t >> 8, tq = t & 255, rg = tq >> 4, cg = tq & 15;
        float4 a4[4];
        gemm_tile(shx, W2_4, q * 64, rg, cg, a4);
        int row0 = q * 64;
        *(float4*)&shx[(row0 + rg * 4 + 0) * 68 + cg * 4] = a4[0];
        *(float4*)&shx[(row0 + rg * 4 + 1) * 68 + cg * 4] = a4[1];
        *(float4*)&shx[(row0 + rg * 4 + 2) * 68 + cg * 4] = a4[2];
        *(float4*)&shx[(row0 + rg * 4 + 3) * 68 + cg * 4] = a4[3];
    }
    __syncthreads();
    // ---- tail2: hist/perm ----
    for (int i = t; i < 256; i += 1024) atomicAdd(&hist[min(cnt[i], 63)], 1);
    __syncthreads();
    if (t < 64) {
        int v = hist[t], s = v;
#pragma unroll
        for (int off = 1; off < 64; off <<= 1) {
            int u = __shfl_up(s, off, 64);
            if (lane >= off) s += u;
        }
        hist[t] = s - v;
    }
    __syncthreads();
    for (int i = t; i < 256; i += 1024) {
        int pos = atomicAdd(&hist[min(cnt[i], 63)], 1);
        perm[pos] = i;
    }
    __syncthreads();
    // ---- conv2 (LPN=4, QF=4; pairs from LDS lp) ----
    {
        int idx2 = t >> 2, half = t & 3, fb = half * 4;
        int nl = perm[idx2];
        int st = rstl[nl], cn = cnt[nl];
        float di = sdinv[nl], dii = di * di;
        const int2* pb = lp + st;
        float4 acc[4];
#pragma unroll
        for (int c = 0; c < 4; ++c) {
            float4 xv = *(const float4*)&shx[nl * 68 + (fb + c) * 4];
            acc[c].x = fmaf(xv.x, dii, sbw[(fb + c) * 4 + 0]);
            acc[c].y = fmaf(xv.y, dii, sbw[(fb + c) * 4 + 1]);
            acc[c].z = fmaf(xv.z, dii, sbw[(fb + c) * 4 + 2]);
            acc[c].w = fmaf(xv.w, dii, sbw[(fb + c) * 4 + 3]);
        }
        int2 p0 = (cn > 0) ? pb[0] : make_int2(0, 0);
        int2 p1 = (cn > 1) ? pb[1] : make_int2(0, 0);
        for (int j = 0; j < cn; ++j) {
            int2 p2 = (j + 2 < cn) ? pb[j + 2] : make_int2(0, 0);
            float cfv = __int_as_float(p0.y);
            int   s   = p0.x;
#pragma unroll
            for (int c = 0; c < 4; ++c)
                acc[c] = f4fma(cfv, *(const float4*)&shx[s * 68 + (fb + c) * 4], acc[c]);
            p0 = p1; p1 = p2;
        }
#pragma unroll
        for (int c = 0; c < 4; ++c) {
            acc[c].x = fmaxf(acc[c].x, 0.f); acc[c].y = fmaxf(acc[c].y, 0.f);
            acc[c].z = fmaxf(acc[c].z, 0.f); acc[c].w = fmaxf(acc[c].w, 0.f);
        }
        __syncthreads();
#pragma unroll
        for (int c = 0; c < 4; ++c)
            *(float4*)&shx[nl * 68 + (fb + c) * 4] = acc[c];
    }
    __syncthreads();
    // ---- hp2 ----
    if (t < 512) {
        int wv8 = t >> 6, sub4 = (t >> 4) & 3;
        float4 w4 = wp2_4[lane16];
#pragma unroll
        for (int p = 0; p < 8; ++p) {
            int n2 = p * 32 + wv8 * 4 + sub4;
            float4 a = *(const float4*)&shx[n2 * 68 + lane16 * 4];
            float tt = a.x * w4.x + a.y * w4.y + a.z * w4.z + a.w * w4.w;
            tt += __shfl_xor(tt, 1, 64); tt += __shfl_xor(tt, 2, 64);
            tt += __shfl_xor(tt, 4, 64); tt += __shfl_xor(tt, 8, 64);
            if (lane16 == 0) shp[n2] = tt;
        }
    }
    __syncthreads();
    // ---- score2 ----
    if (t < 256) {
        int i = perm[t];
        int st = rstl[i], cn = cnt[i];
        float di = sdinv[i];
        const int2* pb = lp + st;
        float a = fmaf(shp[i], di * di, bp2[0]);
        int2 q0 = (cn > 0) ? pb[0] : make_int2(0, 0);
        int2 q1 = (cn > 1) ? pb[1] : make_int2(0, 0);
        for (int j = 0; j < cn; ++j) {
            int2 q2v = (j + 2 < cn) ? pb[j + 2] : make_int2(0, 0);
            a = fmaf(__int_as_float(q0.y), shp[q0.x], a);
            q0 = q1; q1 = q2v;
        }
        ssc[i] = a;
    }
    __syncthreads();
    // ---- rank2 (4 partials per node) ----
    {
        int part = t >> 8, i = t & 255;
        float si = ssc[i];
        int j0 = part * 64, rank = 0;
        for (int j = j0; j < j0 + 64; j += 4) {
            float4 sj = *(const float4*)&ssc[j];
            rank += (sj.x > si) || (sj.x == si && j     < i);
            rank += (sj.y > si) || (sj.y == si && j + 1 < i);
            rank += (sj.z > si) || (sj.z == si && j + 2 < i);
            rank += (sj.w > si) || (sj.w == si && j + 3 < i);
        }
        atomicAdd(&rnk[i], rank);
    }
    __syncthreads();
    // ---- readout2 + final out ----
    {
        float4 mx = make_float4(-3.402823466e38f, -3.402823466e38f, -3.402823466e38f, -3.402823466e38f);
        float4 sm = make_float4(0.f, 0.f, 0.f, 0.f);
        if (t < 512) {
            int wv8 = t >> 6, sub4 = (t >> 4) & 3;
#pragma unroll
            for (int p = 0; p < 8; ++p) {
                int n2 = p * 32 + wv8 * 4 + sub4;
                int r = rnk[n2];
                if (r < 128) {
                    float gt = tanhf(ssc[n2]);
                    float4 v = *(const float4*)&shx[n2 * 68 + lane16 * 4];
                    v.x *= gt; v.y *= gt; v.z *= gt; v.w *= gt;
                    mx.x = fmaxf(mx.x, v.x); mx.y = fmaxf(mx.y, v.y);
                    mx.z = fmaxf(mx.z, v.z); mx.w = fmaxf(mx.w, v.w);
                    sm.x += v.x; sm.y += v.y; sm.z += v.z; sm.w += v.w;
                }
            }
        }
        int grp = t >> 4;
        __syncthreads();
        if (t < 512) redx[grp * 16 + lane16] = mx;
        __syncthreads();
        float mr[4] = {0, 0, 0, 0};
        if (grp == 0) {
#pragma unroll
            for (int u = 1; u < 32; ++u) {
                float4 a = redx[u * 16 + lane16];
                mx.x = fmaxf(mx.x, a.x); mx.y = fmaxf(mx.y, a.y);
                mx.z = fmaxf(mx.z, a.z); mx.w = fmaxf(mx.w, a.w);
            }
            mr[0] = mx.x; mr[1] = mx.y; mr[2] = mx.z; mr[3] = mx.w;
        }
        __syncthreads();
        if (t < 512) redx[grp * 16 + lane16] = sm;
        __syncthreads();
        if (grp == 0) {
#pragma unroll
            for (int u = 1; u < 32; ++u) {
                float4 b = redx[u * 16 + lane16];
                sm.x += b.x; sm.y += b.y; sm.z += b.z; sm.w += b.w;
            }
            float invK = 1.f / 128.f;
            int c = lane16 * 4;
            float ar[4] = {sm.x * invK, sm.y * invK, sm.z * invK, sm.w * invK};
#pragma unroll
            for (int u = 0; u < 4; ++u) {
                out[g * 128 + c + u]      = 0.5f * (x1rs[c + u]      + mr[u]);
                out[g * 128 + 64 + c + u] = 0.5f * (x1rs[64 + c + u] + ar[u]);
            }
        }
    }
}

extern "C" void kernel_launch(void* const* d_in, const int* in_sizes, int n_in,
                              void* d_out, int out_size, void* d_ws, size_t ws_size,
                              hipStream_t stream) {
    const float* x    = (const float*)d_in[0];
    const float* eatt = (const float*)d_in[1];
    const float* W1   = (const float*)d_in[2];
    const float* b1   = (const float*)d_in[3];
    const float* Wp1  = (const float*)d_in[4];
    const float* bp1  = (const float*)d_in[5];
    const float* W2   = (const float*)d_in[6];
    const float* b2   = (const float*)d_in[7];
    const float* Wp2  = (const float*)d_in[8];
    const float* bp2  = (const float*)d_in[9];
    const int*   esrc = (const int*)d_in[10];
    const int*   edst = (const int*)d_in[11];
    float* out = (float*)d_out;

    int2* prs = (int2*)d_ws;                     // [NE] only workspace user

    mega_kernel<<<BG, 1024, 0, stream>>>(
        esrc, edst, eatt, prs, (const float4*)x,
        (const float4*)W1, (const float4*)b1, (const float4*)Wp1, bp1,
        (const float4*)W2, (const float4*)b2, (const float4*)Wp2, bp2,
        out);
}

// Round 12
// 207.854 us; speedup vs baseline: 1.7273x; 1.7273x over previous
//
#include <hip/hip_runtime.h>
#include <math.h>

#define BG   256                   // graphs
#define NN   512                   // nodes per graph
#define EPG  (NN * 16)             // 8192 edges per graph
#define NE   (BG * EPG)            // 2097152 edges

__device__ __forceinline__ float4 f4fma(float s, float4 a, float4 c) {
    c.x = fmaf(s, a.x, c.x); c.y = fmaf(s, a.y, c.y);
    c.z = fmaf(s, a.z, c.z); c.w = fmaf(s, a.w, c.w);
    return c;
}

// one 64x64 GEMM tile, r16-verbatim FMA order. W from global (L1-resident).
__device__ __forceinline__ void gemm_tile(const float* __restrict__ shx,
                                          const float4* __restrict__ W4,
                                          int row0, int rg, int cg, float4 a[4]) {
    float4 acc0 = make_float4(0.f, 0.f, 0.f, 0.f);
    float4 acc1 = acc0, acc2 = acc0, acc3 = acc0;
#pragma unroll
    for (int k4 = 0; k4 < 16; ++k4) {
        float4 xv0 = *(const float4*)&shx[(row0 + rg * 4 + 0) * 68 + k4 * 4];
        float4 xv1 = *(const float4*)&shx[(row0 + rg * 4 + 1) * 68 + k4 * 4];
        float4 xv2 = *(const float4*)&shx[(row0 + rg * 4 + 2) * 68 + k4 * 4];
        float4 xv3 = *(const float4*)&shx[(row0 + rg * 4 + 3) * 68 + k4 * 4];
        float4 wv0 = W4[(k4 * 4 + 0) * 16 + cg];
        float4 wv1 = W4[(k4 * 4 + 1) * 16 + cg];
        float4 wv2 = W4[(k4 * 4 + 2) * 16 + cg];
        float4 wv3 = W4[(k4 * 4 + 3) * 16 + cg];
        acc0 = f4fma(xv0.x, wv0, acc0); acc0 = f4fma(xv0.y, wv1, acc0);
        acc0 = f4fma(xv0.z, wv2, acc0); acc0 = f4fma(xv0.w, wv3, acc0);
        acc1 = f4fma(xv1.x, wv0, acc1); acc1 = f4fma(xv1.y, wv1, acc1);
        acc1 = f4fma(xv1.z, wv2, acc1); acc1 = f4fma(xv1.w, wv3, acc1);
        acc2 = f4fma(xv2.x, wv0, acc2); acc2 = f4fma(xv2.y, wv1, acc2);
        acc2 = f4fma(xv2.z, wv2, acc2); acc2 = f4fma(xv2.w, wv3, acc2);
        acc3 = f4fma(xv3.x, wv0, acc3); acc3 = f4fma(xv3.y, wv1, acc3);
        acc3 = f4fma(xv3.z, wv2, acc3); acc3 = f4fma(xv3.w, wv3, acc3);
    }
    a[0] = acc0; a[1] = acc1; a[2] = acc2; a[3] = acc3;
}

// ---- r23: r21 (best verified: 118.4us kernel) + hp folded into conv ----
// epilogue with EXACT reduction-tree order (bitwise-identical shp):
// per-chunk dot left-to-right, per-lane tree ((p0+p1)+(p2+p3))+((p4+p5)+
// (p6+p7)) = shfl_xor offsets 1/2/4, then tp+=shfl_xor(tp,1[,2]) = offsets
// 8 (and 4,8) in lane-0 association. Deletes hp1/hp2 phases (8K+2K LDS
// reads, 2 barriers). r22 lesson: GEMM barriers are load-bearing register-
// pressure fences at the 64-VGPR cap -- restored to r21 form.
__global__ __launch_bounds__(1024)
void mega_kernel(const int* __restrict__ esrc, const int* __restrict__ edst,
                 const float* __restrict__ eatt, int2* __restrict__ pairs,
                 const float4* __restrict__ X4,
                 const float4* __restrict__ W1_4, const float4* __restrict__ b1_4,
                 const float4* __restrict__ wp1_4, const float* __restrict__ bp1,
                 const float4* __restrict__ W2_4, const float4* __restrict__ b2_4,
                 const float4* __restrict__ wp2_4, const float* __restrict__ bp2,
                 float* __restrict__ out) {
    __shared__ __align__(16) float smem[40720];
    float* shx  = smem;                           // [512*68]
    float* S    = smem + 34816;
    int*   cnt   = (int*)S;                       // [512]
    int*   rstl  = (int*)S + 512;                 // [512]
    float* sdinv = S + 1024;                      // [512]
    int*   perm  = (int*)S + 1536;                // [512] (alias: nor)
    int*   scn   = (int*)S + 2048;                // [512] (alias: shp)
    float* shp   = S + 2048;
    float* wsum  = S + 2560;                      // [512] (alias: ssc)
    float* ssc   = S + 2560;
    int*   rnk   = (int*)S + 3072;                // [512]
    float* sbw   = S + 3584;                      // [64]
    int*   hist  = (int*)S + 3648;                // [64]
    int*   wtot  = (int*)S + 3712;                // [16]
    float* x1rs  = S + 3728;                      // [128]
    float4* redx = (float4*)(S + 3856);           // [512 f4] readout scratch
    float* wsum2 = S + 3856;                      // [256] stage2 (redx dead then)
    int2*  lp    = (int2*)&shx[256 * 68];         // [8192] stage2 pairs overlay

    int g = blockIdx.x, nb1 = g * NN, e0 = g * EPG;
    int t = threadIdx.x;
    int lane16 = t & 15, lane = t & 63;

    const int4*   edst4 = (const int4*)(edst + e0);
    const int4*   esrc4 = (const int4*)(esrc + e0);
    const float4* eatt4 = (const float4*)(eatt + e0);

    // ================= STAGE 1 =================
    // ---- CSR1, 2-pass; lp1 = 8192 int2 over free shx ----
    for (int i = t; i < NN; i += 1024) { cnt[i] = 0; wsum[i] = 0.f; }
    __syncthreads();
    {   // pass A: count (no esrc needed; regs die here)
        int ed[8]; float ea[8];
#pragma unroll
        for (int c = 0; c < 2; ++c) {
            int ch = t + c * 1024;
            int4 dd = edst4[ch]; float4 ww = eatt4[ch];
            ed[c*4+0]=dd.x; ed[c*4+1]=dd.y; ed[c*4+2]=dd.z; ed[c*4+3]=dd.w;
            ea[c*4+0]=ww.x; ea[c*4+1]=ww.y; ea[c*4+2]=ww.z; ea[c*4+3]=ww.w;
        }
#pragma unroll
        for (int j = 0; j < 8; ++j) {
            int dl = ed[j] - nb1;
            atomicAdd(&cnt[dl], 1);
            atomicAdd(&wsum[dl], ea[j]);
        }
    }
    __syncthreads();
    {   // scan (r18-verbatim)
        int wv = t >> 6;
        int xval = (t < NN) ? cnt[t] : 0;
        int xs = xval;
#pragma unroll
        for (int off = 1; off < 64; off <<= 1) {
            int v = __shfl_up(xs, off, 64);
            if (lane >= off) xs += v;
        }
        if (lane == 63) wtot[wv] = xs;
        __syncthreads();
        int woff = 0;
#pragma unroll
        for (int w = 0; w < 16; ++w) { int wt = wtot[w]; if (w < wv) woff += wt; }
        xs += woff;
        if (t < NN) {
            int st = xs - xval;
            rstl[t] = st;
            sdinv[t] = rsqrtf(wsum[t] + 1.0f);
            scn[t] = st;
        }
    }
    __syncthreads();
    {   // pass B: reload edges, cf, scatter into lp1 (full 8192)
        int2* lp1 = (int2*)smem;
        int ed[8], es[8]; float ea[8];
#pragma unroll
        for (int c = 0; c < 2; ++c) {
            int ch = t + c * 1024;
            int4 dd = edst4[ch]; int4 ss = esrc4[ch]; float4 ww = eatt4[ch];
            ed[c*4+0]=dd.x; ed[c*4+1]=dd.y; ed[c*4+2]=dd.z; ed[c*4+3]=dd.w;
            es[c*4+0]=ss.x; es[c*4+1]=ss.y; es[c*4+2]=ss.z; es[c*4+3]=ss.w;
            ea[c*4+0]=ww.x; ea[c*4+1]=ww.y; ea[c*4+2]=ww.z; ea[c*4+3]=ww.w;
        }
#pragma unroll
        for (int j = 0; j < 8; ++j) {
            int dl = ed[j] - nb1, sl = es[j] - nb1;
            float cf = sdinv[dl] * ea[j] * sdinv[sl];
            int slot = atomicAdd(&scn[dl], 1);
            lp1[slot] = make_int2(sl, __float_as_int(cf));
        }
        __syncthreads();
        for (int k = t; k < EPG; k += 1024) pairs[e0 + k] = lp1[k];
    }
    __syncthreads();
    // ---- stage x + inits ----
    for (int i = t; i < NN * 16; i += 1024) {
        int r = i >> 4, c4 = i & 15;
        *(float4*)&shx[r * 68 + c4 * 4] = X4[(size_t)nb1 * 16 + i];
    }
    if (t < 64) { sbw[t] = ((const float*)b1_4)[t]; hist[t] = 0; }
    for (int i = t; i < NN; i += 1024) rnk[i] = 0;
    __syncthreads();
    // ---- GEMM1 (8 tiles, r21 form: compute both, barrier, write both) ----
    {
        int q = t >> 8, tq = t & 255, rg = tq >> 4, cg = tq & 15;
        float4 ac[2][4];
#pragma unroll
        for (int tt = 0; tt < 2; ++tt)
            gemm_tile(shx, W1_4, (tt * 4 + q) * 64, rg, cg, ac[tt]);
        __syncthreads();
#pragma unroll
        for (int tt = 0; tt < 2; ++tt) {
            int row0 = (tt * 4 + q) * 64;
            *(float4*)&shx[(row0 + rg * 4 + 0) * 68 + cg * 4] = ac[tt][0];
            *(float4*)&shx[(row0 + rg * 4 + 1) * 68 + cg * 4] = ac[tt][1];
            *(float4*)&shx[(row0 + rg * 4 + 2) * 68 + cg * 4] = ac[tt][2];
            *(float4*)&shx[(row0 + rg * 4 + 3) * 68 + cg * 4] = ac[tt][3];
        }
    }
    __syncthreads();
    // ---- tail1: hist/perm ----
    for (int i = t; i < NN; i += 1024) atomicAdd(&hist[min(cnt[i], 63)], 1);
    __syncthreads();
    if (t < 64) {
        int v = hist[t], s = v;
#pragma unroll
        for (int off = 1; off < 64; off <<= 1) {
            int u = __shfl_up(s, off, 64);
            if (lane >= off) s += u;
        }
        hist[t] = s - v;
    }
    __syncthreads();
    for (int i = t; i < NN; i += 1024) {
        int pos = atomicAdd(&hist[min(cnt[i], 63)], 1);
        perm[pos] = i;
    }
    __syncthreads();
    // ---- conv1 (LPN=2, QF=8) + fused hp1 (exact-order tree) ----
    {
        int idx2 = t >> 1, half = t & 1, fb = half * 8;
        int nl = perm[idx2];
        int st = rstl[nl], cn = cnt[nl];
        float di = sdinv[nl], dii = di * di;
        const int2* pb = pairs + e0 + st;
        float4 acc[8];
#pragma unroll
        for (int c = 0; c < 8; ++c) {
            float4 xv = *(const float4*)&shx[nl * 68 + (fb + c) * 4];
            acc[c].x = fmaf(xv.x, dii, sbw[(fb + c) * 4 + 0]);
            acc[c].y = fmaf(xv.y, dii, sbw[(fb + c) * 4 + 1]);
            acc[c].z = fmaf(xv.z, dii, sbw[(fb + c) * 4 + 2]);
            acc[c].w = fmaf(xv.w, dii, sbw[(fb + c) * 4 + 3]);
        }
        int2 p0 = (cn > 0) ? pb[0] : make_int2(0, 0);
        int2 p1 = (cn > 1) ? pb[1] : make_int2(0, 0);
        for (int j = 0; j < cn; ++j) {
            int2 p2 = (j + 2 < cn) ? pb[j + 2] : make_int2(0, 0);
            float cfv = __int_as_float(p0.y);
            int   s   = p0.x;
#pragma unroll
            for (int c = 0; c < 8; ++c)
                acc[c] = f4fma(cfv, *(const float4*)&shx[s * 68 + (fb + c) * 4], acc[c]);
            p0 = p1; p1 = p2;
        }
#pragma unroll
        for (int c = 0; c < 8; ++c) {
            acc[c].x = fmaxf(acc[c].x, 0.f); acc[c].y = fmaxf(acc[c].y, 0.f);
            acc[c].z = fmaxf(acc[c].z, 0.f); acc[c].w = fmaxf(acc[c].w, 0.f);
        }
        // fused hp1: p_c = dot(acc[c], wp[fb+c]) left-to-right; lane tree
        // ((p0+p1)+(p2+p3))+((p4+p5)+(p6+p7)); cross-half via shfl_xor(1).
        {
            float p[8];
#pragma unroll
            for (int c = 0; c < 8; ++c) {
                float4 wc = wp1_4[fb + c];
                p[c] = acc[c].x * wc.x + acc[c].y * wc.y
                     + acc[c].z * wc.z + acc[c].w * wc.w;
            }
            float s01 = p[0] + p[1], s23 = p[2] + p[3];
            float s45 = p[4] + p[5], s67 = p[6] + p[7];
            float tp = (s01 + s23) + (s45 + s67);
            tp = tp + __shfl_xor(tp, 1, 64);     // own(T0-7) + other(T8-15)
            if (half == 0) shp[nl] = tp;
        }
        __syncthreads();                     // all conv reads of hx complete
#pragma unroll
        for (int c = 0; c < 8; ++c)
            *(float4*)&shx[nl * 68 + (fb + c) * 4] = acc[c];
    }
    __syncthreads();
    // ---- score1 (shp ready from fused conv) ----
    if (t < NN) {
        int i = perm[t];
        int st = rstl[i], cn = cnt[i];
        float di = sdinv[i];
        const int2* pb = pairs + e0 + st;
        float a = fmaf(shp[i], di * di, bp1[0]);
        int2 q0 = (cn > 0) ? pb[0] : make_int2(0, 0);
        int2 q1 = (cn > 1) ? pb[1] : make_int2(0, 0);
        for (int j = 0; j < cn; ++j) {
            int2 q2v = (j + 2 < cn) ? pb[j + 2] : make_int2(0, 0);
            a = fmaf(__int_as_float(q0.y), shp[q0.x], a);
            q0 = q1; q1 = q2v;
        }
        ssc[i] = a;
    }
    __syncthreads();
    // ---- rank1 (2 partials per node) ----
    {
        int part = t >> 9, i = t & 511;
        float si = ssc[i];
        int j0 = part * 256, rank = 0;
        for (int j = j0; j < j0 + 256; j += 4) {
            float4 sj = *(const float4*)&ssc[j];
            rank += (sj.x > si) || (sj.x == si && j     < i);
            rank += (sj.y > si) || (sj.y == si && j + 1 < i);
            rank += (sj.z > si) || (sj.z == si && j + 2 < i);
            rank += (sj.w > si) || (sj.w == si && j + 3 < i);
        }
        atomicAdd(&rnk[i], rank);
    }
    __syncthreads();
    // ---- readout1 -> x1rs (2-pass 8KB reduce) ----
    {
        float4 mx = make_float4(-3.402823466e38f, -3.402823466e38f, -3.402823466e38f, -3.402823466e38f);
        float4 sm = make_float4(0.f, 0.f, 0.f, 0.f);
        if (t < 512) {
            int wv8 = t >> 6, sub4 = (t >> 4) & 3;
#pragma unroll
            for (int p = 0; p < 16; ++p) {
                int n2 = p * 32 + wv8 * 4 + sub4;
                int r = rnk[n2];
                if (r < 256) {
                    float gt = tanhf(ssc[n2]);
                    float4 v = *(const float4*)&shx[n2 * 68 + lane16 * 4];
                    v.x *= gt; v.y *= gt; v.z *= gt; v.w *= gt;
                    mx.x = fmaxf(mx.x, v.x); mx.y = fmaxf(mx.y, v.y);
                    mx.z = fmaxf(mx.z, v.z); mx.w = fmaxf(mx.w, v.w);
                    sm.x += v.x; sm.y += v.y; sm.z += v.z; sm.w += v.w;
                }
            }
        }
        int grp = t >> 4;
        __syncthreads();
        if (t < 512) redx[grp * 16 + lane16] = mx;
        __syncthreads();
        float mr[4] = {0, 0, 0, 0};
        if (grp == 0) {
#pragma unroll
            for (int u = 1; u < 32; ++u) {
                float4 a = redx[u * 16 + lane16];
                mx.x = fmaxf(mx.x, a.x); mx.y = fmaxf(mx.y, a.y);
                mx.z = fmaxf(mx.z, a.z); mx.w = fmaxf(mx.w, a.w);
            }
            mr[0] = mx.x; mr[1] = mx.y; mr[2] = mx.z; mr[3] = mx.w;
        }
        __syncthreads();
        if (t < 512) redx[grp * 16 + lane16] = sm;
        __syncthreads();
        if (grp == 0) {
#pragma unroll
            for (int u = 1; u < 32; ++u) {
                float4 b = redx[u * 16 + lane16];
                sm.x += b.x; sm.y += b.y; sm.z += b.z; sm.w += b.w;
            }
            float invK = 1.f / 256.f;
            int c = lane16 * 4;
            float ar[4] = {sm.x * invK, sm.y * invK, sm.z * invK, sm.w * invK};
#pragma unroll
            for (int u = 0; u < 4; ++u) {
                x1rs[c + u]      = mr[u];
                x1rs[64 + c + u] = ar[u];
            }
        }
    }
    // ---- compact: gated selected rows -> shx rows 0..255 ----
    {
        int* nor = perm;                         // perm dead after score1
        __syncthreads();
        for (int i = t; i < NN; i += 1024) {
            int r = rnk[i];
            if (r < 256) nor[r] = i;
        }
        __syncthreads();
        float4 stash[4];
        int rr[4], cc[4];
#pragma unroll
        for (int u = 0; u < 4; ++u) {
            int idx = t + u * 1024;
            rr[u] = idx >> 4; cc[u] = idx & 15;
            int n = nor[rr[u]];
            float gt = tanhf(ssc[n]);
            float4 v = *(const float4*)&shx[n * 68 + cc[u] * 4];
            v.x *= gt; v.y *= gt; v.z *= gt; v.w *= gt;
            stash[u] = v;
        }
        __syncthreads();                          // all reads of h complete
#pragma unroll
        for (int u = 0; u < 4; ++u)
            *(float4*)&shx[rr[u] * 68 + cc[u] * 4] = stash[u];
        __syncthreads();
    }

    // ================= STAGE 2 (xn in shx rows 0..255) =================
    // ---- CSR2, 2-pass (remap via stage1 rnk still in LDS) ----
    for (int i = t; i < 256; i += 1024) { cnt[i] = 0; wsum2[i] = 0.f; }
    __syncthreads();
    {   // pass A: load + remap + count (regs die here)
        int ed[8], es[8]; float ea[8];
#pragma unroll
        for (int c = 0; c < 2; ++c) {
            int ch = t + c * 1024;
            int4 dd = edst4[ch]; int4 ss = esrc4[ch]; float4 ww = eatt4[ch];
            ed[c*4+0]=dd.x; ed[c*4+1]=dd.y; ed[c*4+2]=dd.z; ed[c*4+3]=dd.w;
            es[c*4+0]=ss.x; es[c*4+1]=ss.y; es[c*4+2]=ss.z; es[c*4+3]=ss.w;
            ea[c*4+0]=ww.x; ea[c*4+1]=ww.y; ea[c*4+2]=ww.z; ea[c*4+3]=ww.w;
        }
#pragma unroll
        for (int j = 0; j < 8; ++j) {
            int rd = rnk[ed[j] - nb1], rs = rnk[es[j] - nb1];
            if (rd < 256 && rs < 256) {
                atomicAdd(&cnt[rd], 1);
                atomicAdd(&wsum2[rd], ea[j]);
            }
        }
    }
    __syncthreads();
    {   // scan2
        int wv = t >> 6;
        int xval = 0, xs = 0;
        if (t < 256) {
            xval = cnt[t];
            xs = xval;
#pragma unroll
            for (int off = 1; off < 64; off <<= 1) {
                int v = __shfl_up(xs, off, 64);
                if (lane >= off) xs += v;
            }
            if (lane == 63) wtot[wv] = xs;
        }
        __syncthreads();
        if (t < 256) {
            int woff = 0;
#pragma unroll
            for (int w = 0; w < 4; ++w) { int wt = wtot[w]; if (w < wv) woff += wt; }
            xs += woff;
            int st = xs - xval;
            rstl[t] = st;
            sdinv[t] = rsqrtf(wsum2[t] + 1.0f);
            scn[t] = st;
        }
    }
    __syncthreads();
    {   // pass B: reload + remap + cf + scatter into lp (LDS)
        int ed[8], es[8]; float ea[8];
#pragma unroll
        for (int c = 0; c < 2; ++c) {
            int ch = t + c * 1024;
            int4 dd = edst4[ch]; int4 ss = esrc4[ch]; float4 ww = eatt4[ch];
            ed[c*4+0]=dd.x; ed[c*4+1]=dd.y; ed[c*4+2]=dd.z; ed[c*4+3]=dd.w;
            es[c*4+0]=ss.x; es[c*4+1]=ss.y; es[c*4+2]=ss.z; es[c*4+3]=ss.w;
            ea[c*4+0]=ww.x; ea[c*4+1]=ww.y; ea[c*4+2]=ww.z; ea[c*4+3]=ww.w;
        }
#pragma unroll
        for (int j = 0; j < 8; ++j) {
            int rd = rnk[ed[j] - nb1], rs = rnk[es[j] - nb1];
            if (rd < 256 && rs < 256) {
                float cf = sdinv[rd] * ea[j] * sdinv[rs];
                int slot = atomicAdd(&scn[rd], 1);
                lp[slot] = make_int2(rs, __float_as_int(cf));
            }
        }
    }
    __syncthreads();
    // stage2 inits (after pass B: rnk reads complete)
    if (t < 256) rnk[t] = 0;
    if (t < 64) { sbw[t] = ((const float*)b2_4)[t]; hist[t] = 0; }
    __syncthreads();
    // ---- GEMM2 (4 tiles, r21 form) ----
    {
        int q = t >> 8, tq = t & 255, rg = tq >> 4, cg = tq & 15;
        float4 a4[4];
        gemm_tile(shx, W2_4, q * 64, rg, cg, a4);
        __syncthreads();
        int row0 = q * 64;
        *(float4*)&shx[(row0 + rg * 4 + 0) * 68 + cg * 4] = a4[0];
        *(float4*)&shx[(row0 + rg * 4 + 1) * 68 + cg * 4] = a4[1];
        *(float4*)&shx[(row0 + rg * 4 + 2) * 68 + cg * 4] = a4[2];
        *(float4*)&shx[(row0 + rg * 4 + 3) * 68 + cg * 4] = a4[3];
    }
    __syncthreads();
    // ---- tail2: hist/perm ----
    for (int i = t; i < 256; i += 1024) atomicAdd(&hist[min(cnt[i], 63)], 1);
    __syncthreads();
    if (t < 64) {
        int v = hist[t], s = v;
#pragma unroll
        for (int off = 1; off < 64; off <<= 1) {
            int u = __shfl_up(s, off, 64);
            if (lane >= off) s += u;
        }
        hist[t] = s - v;
    }
    __syncthreads();
    for (int i = t; i < 256; i += 1024) {
        int pos = atomicAdd(&hist[min(cnt[i], 63)], 1);
        perm[pos] = i;
    }
    __syncthreads();
    // ---- conv2 (LPN=4, QF=4; pairs from LDS lp) + fused hp2 ----
    {
        int idx2 = t >> 2, half = t & 3, fb = half * 4;
        int nl = perm[idx2];
        int st = rstl[nl], cn = cnt[nl];
        float di = sdinv[nl], dii = di * di;
        const int2* pb = lp + st;
        float4 acc[4];
#pragma unroll
        for (int c = 0; c < 4; ++c) {
            float4 xv = *(const float4*)&shx[nl * 68 + (fb + c) * 4];
            acc[c].x = fmaf(xv.x, dii, sbw[(fb + c) * 4 + 0]);
            acc[c].y = fmaf(xv.y, dii, sbw[(fb + c) * 4 + 1]);
            acc[c].z = fmaf(xv.z, dii, sbw[(fb + c) * 4 + 2]);
            acc[c].w = fmaf(xv.w, dii, sbw[(fb + c) * 4 + 3]);
        }
        int2 p0 = (cn > 0) ? pb[0] : make_int2(0, 0);
        int2 p1 = (cn > 1) ? pb[1] : make_int2(0, 0);
        for (int j = 0; j < cn; ++j) {
            int2 p2 = (j + 2 < cn) ? pb[j + 2] : make_int2(0, 0);
            float cfv = __int_as_float(p0.y);
            int   s   = p0.x;
#pragma unroll
            for (int c = 0; c < 4; ++c)
                acc[c] = f4fma(cfv, *(const float4*)&shx[s * 68 + (fb + c) * 4], acc[c]);
            p0 = p1; p1 = p2;
        }
#pragma unroll
        for (int c = 0; c < 4; ++c) {
            acc[c].x = fmaxf(acc[c].x, 0.f); acc[c].y = fmaxf(acc[c].y, 0.f);
            acc[c].z = fmaxf(acc[c].z, 0.f); acc[c].w = fmaxf(acc[c].w, 0.f);
        }
        // fused hp2: 4 chunks/lane; tree (p0+p1)+(p2+p3) = offs 1,2;
        // shfl_xor(1)=off4 (4-groups), shfl_xor(2)=off8 (8-groups).
        {
            float p[4];
#pragma unroll
            for (int c = 0; c < 4; ++c) {
                float4 wc = wp2_4[fb + c];
                p[c] = acc[c].x * wc.x + acc[c].y * wc.y
                     + acc[c].z * wc.z + acc[c].w * wc.w;
            }
            float tp = (p[0] + p[1]) + (p[2] + p[3]);
            tp = tp + __shfl_xor(tp, 1, 64);
            tp = tp + __shfl_xor(tp, 2, 64);
            if (half == 0) shp[nl] = tp;
        }
        __syncthreads();
#pragma unroll
        for (int c = 0; c < 4; ++c)
            *(float4*)&shx[nl * 68 + (fb + c) * 4] = acc[c];
    }
    __syncthreads();
    // ---- score2 (shp ready from fused conv) ----
    if (t < 256) {
        int i = perm[t];
        int st = rstl[i], cn = cnt[i];
        float di = sdinv[i];
        const int2* pb = lp + st;
        float a = fmaf(shp[i], di * di, bp2[0]);
        int2 q0 = (cn > 0) ? pb[0] : make_int2(0, 0);
        int2 q1 = (cn > 1) ? pb[1] : make_int2(0, 0);
        for (int j = 0; j < cn; ++j) {
            int2 q2v = (j + 2 < cn) ? pb[j + 2] : make_int2(0, 0);
            a = fmaf(__int_as_float(q0.y), shp[q0.x], a);
            q0 = q1; q1 = q2v;
        }
        ssc[i] = a;
    }
    __syncthreads();
    // ---- rank2 (4 partials per node) ----
    {
        int part = t >> 8, i = t & 255;
        float si = ssc[i];
        int j0 = part * 64, rank = 0;
        for (int j = j0; j < j0 + 64; j += 4) {
            float4 sj = *(const float4*)&ssc[j];
            rank += (sj.x > si) || (sj.x == si && j     < i);
            rank += (sj.y > si) || (sj.y == si && j + 1 < i);
            rank += (sj.z > si) || (sj.z == si && j + 2 < i);
            rank += (sj.w > si) || (sj.w == si && j + 3 < i);
        }
        atomicAdd(&rnk[i], rank);
    }
    __syncthreads();
    // ---- readout2 + final out ----
    {
        float4 mx = make_float4(-3.402823466e38f, -3.402823466e38f, -3.402823466e38f, -3.402823466e38f);
        float4 sm = make_float4(0.f, 0.f, 0.f, 0.f);
        if (t < 512) {
            int wv8 = t >> 6, sub4 = (t >> 4) & 3;
#pragma unroll
            for (int p = 0; p < 8; ++p) {
                int n2 = p * 32 + wv8 * 4 + sub4;
                int r = rnk[n2];
                if (r < 128) {
                    float gt = tanhf(ssc[n2]);
                    float4 v = *(const float4*)&shx[n2 * 68 + lane16 * 4];
                    v.x *= gt; v.y *= gt; v.z *= gt; v.w *= gt;
                    mx.x = fmaxf(mx.x, v.x); mx.y = fmaxf(mx.y, v.y);
                    mx.z = fmaxf(mx.z, v.z); mx.w = fmaxf(mx.w, v.w);
                    sm.x += v.x; sm.y += v.y; sm.z += v.z; sm.w += v.w;
                }
            }
        }
        int grp = t >> 4;
        __syncthreads();
        if (t < 512) redx[grp * 16 + lane16] = mx;
        __syncthreads();
        float mr[4] = {0, 0, 0, 0};
        if (grp == 0) {
#pragma unroll
            for (int u = 1; u < 32; ++u) {
                float4 a = redx[u * 16 + lane16];
                mx.x = fmaxf(mx.x, a.x); mx.y = fmaxf(mx.y, a.y);
                mx.z = fmaxf(mx.z, a.z); mx.w = fmaxf(mx.w, a.w);
            }
            mr[0] = mx.x; mr[1] = mx.y; mr[2] = mx.z; mr[3] = mx.w;
        }
        __syncthreads();
        if (t < 512) redx[grp * 16 + lane16] = sm;
        __syncthreads();
        if (grp == 0) {
#pragma unroll
            for (int u = 1; u < 32; ++u) {
                float4 b = redx[u * 16 + lane16];
                sm.x += b.x; sm.y += b.y; sm.z += b.z; sm.w += b.w;
            }
            float invK = 1.f / 128.f;
            int c = lane16 * 4;
            float ar[4] = {sm.x * invK, sm.y * invK, sm.z * invK, sm.w * invK};
#pragma unroll
            for (int u = 0; u < 4; ++u) {
                out[g * 128 + c + u]      = 0.5f * (x1rs[c + u]      + mr[u]);
                out[g * 128 + 64 + c + u] = 0.5f * (x1rs[64 + c + u] + ar[u]);
            }
        }
    }
}

extern "C" void kernel_launch(void* const* d_in, const int* in_sizes, int n_in,
                              void* d_out, int out_size, void* d_ws, size_t ws_size,
                              hipStream_t stream) {
    const float* x    = (const float*)d_in[0];
    const float* eatt = (const float*)d_in[1];
    const float* W1   = (const float*)d_in[2];
    const float* b1   = (const float*)d_in[3];
    const float* Wp1  = (const float*)d_in[4];
    const float* bp1  = (const float*)d_in[5];
    const float* W2   = (const float*)d_in[6];
    const float* b2   = (const float*)d_in[7];
    const float* Wp2  = (const float*)d_in[8];
    const float* bp2  = (const float*)d_in[9];
    const int*   esrc = (const int*)d_in[10];
    const int*   edst = (const int*)d_in[11];
    float* out = (float*)d_out;

    int2* prs = (int2*)d_ws;                     // [NE] only workspace user

    mega_kernel<<<BG, 1024, 0, stream>>>(
        esrc, edst, eatt, prs, (const float4*)x,
        (const float4*)W1, (const float4*)b1, (const float4*)Wp1, bp1,
        (const float4*)W2, (const float4*)b2, (const float4*)Wp2, bp2,
        out);
}

// Round 13
// 207.259 us; speedup vs baseline: 1.7322x; 1.0029x over previous
//
#include <hip/hip_runtime.h>
#include <math.h>

#define BG   256                   // graphs
#define NN   512                   // nodes per graph
#define EPG  (NN * 16)             // 8192 edges per graph
#define NE   (BG * EPG)            // 2097152 edges

__device__ __forceinline__ float4 f4fma(float s, float4 a, float4 c) {
    c.x = fmaf(s, a.x, c.x); c.y = fmaf(s, a.y, c.y);
    c.z = fmaf(s, a.z, c.z); c.w = fmaf(s, a.w, c.w);
    return c;
}

// one 64x64 GEMM tile, r16-verbatim FMA order. W from global (L1-resident).
__device__ __forceinline__ void gemm_tile(const float* __restrict__ shx,
                                          const float4* __restrict__ W4,
                                          int row0, int rg, int cg, float4 a[4]) {
    float4 acc0 = make_float4(0.f, 0.f, 0.f, 0.f);
    float4 acc1 = acc0, acc2 = acc0, acc3 = acc0;
#pragma unroll
    for (int k4 = 0; k4 < 16; ++k4) {
        float4 xv0 = *(const float4*)&shx[(row0 + rg * 4 + 0) * 68 + k4 * 4];
        float4 xv1 = *(const float4*)&shx[(row0 + rg * 4 + 1) * 68 + k4 * 4];
        float4 xv2 = *(const float4*)&shx[(row0 + rg * 4 + 2) * 68 + k4 * 4];
        float4 xv3 = *(const float4*)&shx[(row0 + rg * 4 + 3) * 68 + k4 * 4];
        float4 wv0 = W4[(k4 * 4 + 0) * 16 + cg];
        float4 wv1 = W4[(k4 * 4 + 1) * 16 + cg];
        float4 wv2 = W4[(k4 * 4 + 2) * 16 + cg];
        float4 wv3 = W4[(k4 * 4 + 3) * 16 + cg];
        acc0 = f4fma(xv0.x, wv0, acc0); acc0 = f4fma(xv0.y, wv1, acc0);
        acc0 = f4fma(xv0.z, wv2, acc0); acc0 = f4fma(xv0.w, wv3, acc0);
        acc1 = f4fma(xv1.x, wv0, acc1); acc1 = f4fma(xv1.y, wv1, acc1);
        acc1 = f4fma(xv1.z, wv2, acc1); acc1 = f4fma(xv1.w, wv3, acc1);
        acc2 = f4fma(xv2.x, wv0, acc2); acc2 = f4fma(xv2.y, wv1, acc2);
        acc2 = f4fma(xv2.z, wv2, acc2); acc2 = f4fma(xv2.w, wv3, acc2);
        acc3 = f4fma(xv3.x, wv0, acc3); acc3 = f4fma(xv3.y, wv1, acc3);
        acc3 = f4fma(xv3.z, wv2, acc3); acc3 = f4fma(xv3.w, wv3, acc3);
    }
    a[0] = acc0; a[1] = acc1; a[2] = acc2; a[3] = acc3;
}

// ---- r24: r21 (best: 118.4us kernel) + conv bank-conflict stagger. ----
// Conv gather reads random rows: group (r+c) mod 8 -> balls-in-bins ~2x LDS
// cycles (7.3M conflict cycles measured). Stagger chunk iteration per pair:
// c_i = fb + ((i + (pair - r)) & 7) -> group (pair + i) mod 8 = exactly 4
// pairs/group every step, deterministic. Acc register i permanently owns
// chunk c_i (compile-time reg index, runtime address only -> no scratch).
// Per-chunk j-ascending FMA chains untouched -> bitwise identical.
// conv2 analog: c(h,i) = (4h + i + (quad - r)) & 15, group (q+4h+i) mod 8.
__global__ __launch_bounds__(1024)
void mega_kernel(const int* __restrict__ esrc, const int* __restrict__ edst,
                 const float* __restrict__ eatt, int2* __restrict__ pairs,
                 const float4* __restrict__ X4,
                 const float4* __restrict__ W1_4, const float4* __restrict__ b1_4,
                 const float4* __restrict__ wp1_4, const float* __restrict__ bp1,
                 const float4* __restrict__ W2_4, const float4* __restrict__ b2_4,
                 const float4* __restrict__ wp2_4, const float* __restrict__ bp2,
                 float* __restrict__ out) {
    __shared__ __align__(16) float smem[40720];
    float* shx  = smem;                           // [512*68]
    float* S    = smem + 34816;
    int*   cnt   = (int*)S;                       // [512]
    int*   rstl  = (int*)S + 512;                 // [512]
    float* sdinv = S + 1024;                      // [512]
    int*   perm  = (int*)S + 1536;                // [512] (alias: nor)
    int*   scn   = (int*)S + 2048;                // [512] (alias: shp)
    float* shp   = S + 2048;
    float* wsum  = S + 2560;                      // [512] (alias: ssc)
    float* ssc   = S + 2560;
    int*   rnk   = (int*)S + 3072;                // [512]
    float* sbw   = S + 3584;                      // [64]
    int*   hist  = (int*)S + 3648;                // [64]
    int*   wtot  = (int*)S + 3712;                // [16]
    float* x1rs  = S + 3728;                      // [128]
    float4* redx = (float4*)(S + 3856);           // [512 f4] readout scratch
    float* wsum2 = S + 3856;                      // [256] stage2 (redx dead then)
    int2*  lp    = (int2*)&shx[256 * 68];         // [8192] stage2 pairs overlay

    int g = blockIdx.x, nb1 = g * NN, e0 = g * EPG;
    int t = threadIdx.x;
    int lane16 = t & 15, lane = t & 63;

    const int4*   edst4 = (const int4*)(edst + e0);
    const int4*   esrc4 = (const int4*)(esrc + e0);
    const float4* eatt4 = (const float4*)(eatt + e0);

    // ================= STAGE 1 =================
    // ---- CSR1, 2-pass; lp1 = 8192 int2 over free shx ----
    for (int i = t; i < NN; i += 1024) { cnt[i] = 0; wsum[i] = 0.f; }
    __syncthreads();
    {   // pass A: count (no esrc needed; regs die here)
        int ed[8]; float ea[8];
#pragma unroll
        for (int c = 0; c < 2; ++c) {
            int ch = t + c * 1024;
            int4 dd = edst4[ch]; float4 ww = eatt4[ch];
            ed[c*4+0]=dd.x; ed[c*4+1]=dd.y; ed[c*4+2]=dd.z; ed[c*4+3]=dd.w;
            ea[c*4+0]=ww.x; ea[c*4+1]=ww.y; ea[c*4+2]=ww.z; ea[c*4+3]=ww.w;
        }
#pragma unroll
        for (int j = 0; j < 8; ++j) {
            int dl = ed[j] - nb1;
            atomicAdd(&cnt[dl], 1);
            atomicAdd(&wsum[dl], ea[j]);
        }
    }
    __syncthreads();
    {   // scan (r18-verbatim)
        int wv = t >> 6;
        int xval = (t < NN) ? cnt[t] : 0;
        int xs = xval;
#pragma unroll
        for (int off = 1; off < 64; off <<= 1) {
            int v = __shfl_up(xs, off, 64);
            if (lane >= off) xs += v;
        }
        if (lane == 63) wtot[wv] = xs;
        __syncthreads();
        int woff = 0;
#pragma unroll
        for (int w = 0; w < 16; ++w) { int wt = wtot[w]; if (w < wv) woff += wt; }
        xs += woff;
        if (t < NN) {
            int st = xs - xval;
            rstl[t] = st;
            sdinv[t] = rsqrtf(wsum[t] + 1.0f);
            scn[t] = st;
        }
    }
    __syncthreads();
    {   // pass B: reload edges, cf, scatter into lp1 (full 8192)
        int2* lp1 = (int2*)smem;
        int ed[8], es[8]; float ea[8];
#pragma unroll
        for (int c = 0; c < 2; ++c) {
            int ch = t + c * 1024;
            int4 dd = edst4[ch]; int4 ss = esrc4[ch]; float4 ww = eatt4[ch];
            ed[c*4+0]=dd.x; ed[c*4+1]=dd.y; ed[c*4+2]=dd.z; ed[c*4+3]=dd.w;
            es[c*4+0]=ss.x; es[c*4+1]=ss.y; es[c*4+2]=ss.z; es[c*4+3]=ss.w;
            ea[c*4+0]=ww.x; ea[c*4+1]=ww.y; ea[c*4+2]=ww.z; ea[c*4+3]=ww.w;
        }
#pragma unroll
        for (int j = 0; j < 8; ++j) {
            int dl = ed[j] - nb1, sl = es[j] - nb1;
            float cf = sdinv[dl] * ea[j] * sdinv[sl];
            int slot = atomicAdd(&scn[dl], 1);
            lp1[slot] = make_int2(sl, __float_as_int(cf));
        }
        __syncthreads();
        for (int k = t; k < EPG; k += 1024) pairs[e0 + k] = lp1[k];
    }
    __syncthreads();
    // ---- stage x + inits ----
    for (int i = t; i < NN * 16; i += 1024) {
        int r = i >> 4, c4 = i & 15;
        *(float4*)&shx[r * 68 + c4 * 4] = X4[(size_t)nb1 * 16 + i];
    }
    if (t < 64) { sbw[t] = ((const float*)b1_4)[t]; hist[t] = 0; }
    for (int i = t; i < NN; i += 1024) rnk[i] = 0;
    __syncthreads();
    // ---- GEMM1 (8 tiles, r21 form: compute both, barrier, write both) ----
    {
        int q = t >> 8, tq = t & 255, rg = tq >> 4, cg = tq & 15;
        float4 ac[2][4];
#pragma unroll
        for (int tt = 0; tt < 2; ++tt)
            gemm_tile(shx, W1_4, (tt * 4 + q) * 64, rg, cg, ac[tt]);
        __syncthreads();
#pragma unroll
        for (int tt = 0; tt < 2; ++tt) {
            int row0 = (tt * 4 + q) * 64;
            *(float4*)&shx[(row0 + rg * 4 + 0) * 68 + cg * 4] = ac[tt][0];
            *(float4*)&shx[(row0 + rg * 4 + 1) * 68 + cg * 4] = ac[tt][1];
            *(float4*)&shx[(row0 + rg * 4 + 2) * 68 + cg * 4] = ac[tt][2];
            *(float4*)&shx[(row0 + rg * 4 + 3) * 68 + cg * 4] = ac[tt][3];
        }
    }
    __syncthreads();
    // ---- tail1: hist/perm ----
    for (int i = t; i < NN; i += 1024) atomicAdd(&hist[min(cnt[i], 63)], 1);
    __syncthreads();
    if (t < 64) {
        int v = hist[t], s = v;
#pragma unroll
        for (int off = 1; off < 64; off <<= 1) {
            int u = __shfl_up(s, off, 64);
            if (lane >= off) s += u;
        }
        hist[t] = s - v;
    }
    __syncthreads();
    for (int i = t; i < NN; i += 1024) {
        int pos = atomicAdd(&hist[min(cnt[i], 63)], 1);
        perm[pos] = i;
    }
    __syncthreads();
    // ---- conv1 (LPN=2, QF=8, depth-2 prefetch) + bank stagger ----
    {
        int idx2 = t >> 1, half = t & 1, fb = half * 8;
        int nl = perm[idx2];
        int st = rstl[nl], cn = cnt[nl];
        float di = sdinv[nl], dii = di * di;
        const int2* pb = pairs + e0 + st;
        int rot = (((t >> 1) & 31) - nl) & 7;     // pair stagger
        int co[8];                                 // float offsets of owned chunks
#pragma unroll
        for (int i = 0; i < 8; ++i) co[i] = (fb + ((i + rot) & 7)) * 4;
        float4 acc[8];
#pragma unroll
        for (int i = 0; i < 8; ++i) {
            float4 xv = *(const float4*)&shx[nl * 68 + co[i]];
            acc[i].x = fmaf(xv.x, dii, sbw[co[i] + 0]);
            acc[i].y = fmaf(xv.y, dii, sbw[co[i] + 1]);
            acc[i].z = fmaf(xv.z, dii, sbw[co[i] + 2]);
            acc[i].w = fmaf(xv.w, dii, sbw[co[i] + 3]);
        }
        int2 p0 = (cn > 0) ? pb[0] : make_int2(0, 0);
        int2 p1 = (cn > 1) ? pb[1] : make_int2(0, 0);
        for (int j = 0; j < cn; ++j) {
            int2 p2 = (j + 2 < cn) ? pb[j + 2] : make_int2(0, 0);
            float cfv = __int_as_float(p0.y);
            int   s   = p0.x;
#pragma unroll
            for (int i = 0; i < 8; ++i)
                acc[i] = f4fma(cfv, *(const float4*)&shx[s * 68 + co[i]], acc[i]);
            p0 = p1; p1 = p2;
        }
#pragma unroll
        for (int i = 0; i < 8; ++i) {
            acc[i].x = fmaxf(acc[i].x, 0.f); acc[i].y = fmaxf(acc[i].y, 0.f);
            acc[i].z = fmaxf(acc[i].z, 0.f); acc[i].w = fmaxf(acc[i].w, 0.f);
        }
        __syncthreads();                     // all conv reads of hx complete
#pragma unroll
        for (int i = 0; i < 8; ++i)
            *(float4*)&shx[nl * 68 + co[i]] = acc[i];
    }
    __syncthreads();
    // ---- hp1 ----
    if (t < 512) {
        int wv8 = t >> 6, sub4 = (t >> 4) & 3;
        float4 w4 = wp1_4[lane16];
#pragma unroll
        for (int p = 0; p < 16; ++p) {
            int n2 = p * 32 + wv8 * 4 + sub4;
            float4 a = *(const float4*)&shx[n2 * 68 + lane16 * 4];
            float tt = a.x * w4.x + a.y * w4.y + a.z * w4.z + a.w * w4.w;
            tt += __shfl_xor(tt, 1, 64); tt += __shfl_xor(tt, 2, 64);
            tt += __shfl_xor(tt, 4, 64); tt += __shfl_xor(tt, 8, 64);
            if (lane16 == 0) shp[n2] = tt;
        }
    }
    __syncthreads();
    // ---- score1 ----
    if (t < NN) {
        int i = perm[t];
        int st = rstl[i], cn = cnt[i];
        float di = sdinv[i];
        const int2* pb = pairs + e0 + st;
        float a = fmaf(shp[i], di * di, bp1[0]);
        int2 q0 = (cn > 0) ? pb[0] : make_int2(0, 0);
        int2 q1 = (cn > 1) ? pb[1] : make_int2(0, 0);
        for (int j = 0; j < cn; ++j) {
            int2 q2v = (j + 2 < cn) ? pb[j + 2] : make_int2(0, 0);
            a = fmaf(__int_as_float(q0.y), shp[q0.x], a);
            q0 = q1; q1 = q2v;
        }
        ssc[i] = a;
    }
    __syncthreads();
    // ---- rank1 (2 partials per node) ----
    {
        int part = t >> 9, i = t & 511;
        float si = ssc[i];
        int j0 = part * 256, rank = 0;
        for (int j = j0; j < j0 + 256; j += 4) {
            float4 sj = *(const float4*)&ssc[j];
            rank += (sj.x > si) || (sj.x == si && j     < i);
            rank += (sj.y > si) || (sj.y == si && j + 1 < i);
            rank += (sj.z > si) || (sj.z == si && j + 2 < i);
            rank += (sj.w > si) || (sj.w == si && j + 3 < i);
        }
        atomicAdd(&rnk[i], rank);
    }
    __syncthreads();
    // ---- readout1 -> x1rs (2-pass 8KB reduce) ----
    {
        float4 mx = make_float4(-3.402823466e38f, -3.402823466e38f, -3.402823466e38f, -3.402823466e38f);
        float4 sm = make_float4(0.f, 0.f, 0.f, 0.f);
        if (t < 512) {
            int wv8 = t >> 6, sub4 = (t >> 4) & 3;
#pragma unroll
            for (int p = 0; p < 16; ++p) {
                int n2 = p * 32 + wv8 * 4 + sub4;
                int r = rnk[n2];
                if (r < 256) {
                    float gt = tanhf(ssc[n2]);
                    float4 v = *(const float4*)&shx[n2 * 68 + lane16 * 4];
                    v.x *= gt; v.y *= gt; v.z *= gt; v.w *= gt;
                    mx.x = fmaxf(mx.x, v.x); mx.y = fmaxf(mx.y, v.y);
                    mx.z = fmaxf(mx.z, v.z); mx.w = fmaxf(mx.w, v.w);
                    sm.x += v.x; sm.y += v.y; sm.z += v.z; sm.w += v.w;
                }
            }
        }
        int grp = t >> 4;
        __syncthreads();
        if (t < 512) redx[grp * 16 + lane16] = mx;
        __syncthreads();
        float mr[4] = {0, 0, 0, 0};
        if (grp == 0) {
#pragma unroll
            for (int u = 1; u < 32; ++u) {
                float4 a = redx[u * 16 + lane16];
                mx.x = fmaxf(mx.x, a.x); mx.y = fmaxf(mx.y, a.y);
                mx.z = fmaxf(mx.z, a.z); mx.w = fmaxf(mx.w, a.w);
            }
            mr[0] = mx.x; mr[1] = mx.y; mr[2] = mx.z; mr[3] = mx.w;
        }
        __syncthreads();
        if (t < 512) redx[grp * 16 + lane16] = sm;
        __syncthreads();
        if (grp == 0) {
#pragma unroll
            for (int u = 1; u < 32; ++u) {
                float4 b = redx[u * 16 + lane16];
                sm.x += b.x; sm.y += b.y; sm.z += b.z; sm.w += b.w;
            }
            float invK = 1.f / 256.f;
            int c = lane16 * 4;
            float ar[4] = {sm.x * invK, sm.y * invK, sm.z * invK, sm.w * invK};
#pragma unroll
            for (int u = 0; u < 4; ++u) {
                x1rs[c + u]      = mr[u];
                x1rs[64 + c + u] = ar[u];
            }
        }
    }
    // ---- compact: gated selected rows -> shx rows 0..255 ----
    {
        int* nor = perm;                         // perm dead after score1
        __syncthreads();
        for (int i = t; i < NN; i += 1024) {
            int r = rnk[i];
            if (r < 256) nor[r] = i;
        }
        __syncthreads();
        float4 stash[4];
        int rr[4], cc[4];
#pragma unroll
        for (int u = 0; u < 4; ++u) {
            int idx = t + u * 1024;
            rr[u] = idx >> 4; cc[u] = idx & 15;
            int n = nor[rr[u]];
            float gt = tanhf(ssc[n]);
            float4 v = *(const float4*)&shx[n * 68 + cc[u] * 4];
            v.x *= gt; v.y *= gt; v.z *= gt; v.w *= gt;
            stash[u] = v;
        }
        __syncthreads();                          // all reads of h complete
#pragma unroll
        for (int u = 0; u < 4; ++u)
            *(float4*)&shx[rr[u] * 68 + cc[u] * 4] = stash[u];
        __syncthreads();
    }

    // ================= STAGE 2 (xn in shx rows 0..255) =================
    // ---- CSR2, 2-pass (remap via stage1 rnk still in LDS) ----
    for (int i = t; i < 256; i += 1024) { cnt[i] = 0; wsum2[i] = 0.f; }
    __syncthreads();
    {   // pass A: load + remap + count (regs die here)
        int ed[8], es[8]; float ea[8];
#pragma unroll
        for (int c = 0; c < 2; ++c) {
            int ch = t + c * 1024;
            int4 dd = edst4[ch]; int4 ss = esrc4[ch]; float4 ww = eatt4[ch];
            ed[c*4+0]=dd.x; ed[c*4+1]=dd.y; ed[c*4+2]=dd.z; ed[c*4+3]=dd.w;
            es[c*4+0]=ss.x; es[c*4+1]=ss.y; es[c*4+2]=ss.z; es[c*4+3]=ss.w;
            ea[c*4+0]=ww.x; ea[c*4+1]=ww.y; ea[c*4+2]=ww.z; ea[c*4+3]=ww.w;
        }
#pragma unroll
        for (int j = 0; j < 8; ++j) {
            int rd = rnk[ed[j] - nb1], rs = rnk[es[j] - nb1];
            if (rd < 256 && rs < 256) {
                atomicAdd(&cnt[rd], 1);
                atomicAdd(&wsum2[rd], ea[j]);
            }
        }
    }
    __syncthreads();
    {   // scan2
        int wv = t >> 6;
        int xval = 0, xs = 0;
        if (t < 256) {
            xval = cnt[t];
            xs = xval;
#pragma unroll
            for (int off = 1; off < 64; off <<= 1) {
                int v = __shfl_up(xs, off, 64);
                if (lane >= off) xs += v;
            }
            if (lane == 63) wtot[wv] = xs;
        }
        __syncthreads();
        if (t < 256) {
            int woff = 0;
#pragma unroll
            for (int w = 0; w < 4; ++w) { int wt = wtot[w]; if (w < wv) woff += wt; }
            xs += woff;
            int st = xs - xval;
            rstl[t] = st;
            sdinv[t] = rsqrtf(wsum2[t] + 1.0f);
            scn[t] = st;
        }
    }
    __syncthreads();
    {   // pass B: reload + remap + cf + scatter into lp (LDS)
        int ed[8], es[8]; float ea[8];
#pragma unroll
        for (int c = 0; c < 2; ++c) {
            int ch = t + c * 1024;
            int4 dd = edst4[ch]; int4 ss = esrc4[ch]; float4 ww = eatt4[ch];
            ed[c*4+0]=dd.x; ed[c*4+1]=dd.y; ed[c*4+2]=dd.z; ed[c*4+3]=dd.w;
            es[c*4+0]=ss.x; es[c*4+1]=ss.y; es[c*4+2]=ss.z; es[c*4+3]=ss.w;
            ea[c*4+0]=ww.x; ea[c*4+1]=ww.y; ea[c*4+2]=ww.z; ea[c*4+3]=ww.w;
        }
#pragma unroll
        for (int j = 0; j < 8; ++j) {
            int rd = rnk[ed[j] - nb1], rs = rnk[es[j] - nb1];
            if (rd < 256 && rs < 256) {
                float cf = sdinv[rd] * ea[j] * sdinv[rs];
                int slot = atomicAdd(&scn[rd], 1);
                lp[slot] = make_int2(rs, __float_as_int(cf));
            }
        }
    }
    __syncthreads();
    // stage2 inits (after pass B: rnk reads complete)
    if (t < 256) rnk[t] = 0;
    if (t < 64) { sbw[t] = ((const float*)b2_4)[t]; hist[t] = 0; }
    __syncthreads();
    // ---- GEMM2 (4 tiles, r21 form) ----
    {
        int q = t >> 8, tq = t & 255, rg = tq >> 4, cg = tq & 15;
        float4 a4[4];
        gemm_tile(shx, W2_4, q * 64, rg, cg, a4);
        __syncthreads();
        int row0 = q * 64;
        *(float4*)&shx[(row0 + rg * 4 + 0) * 68 + cg * 4] = a4[0];
        *(float4*)&shx[(row0 + rg * 4 + 1) * 68 + cg * 4] = a4[1];
        *(float4*)&shx[(row0 + rg * 4 + 2) * 68 + cg * 4] = a4[2];
        *(float4*)&shx[(row0 + rg * 4 + 3) * 68 + cg * 4] = a4[3];
    }
    __syncthreads();
    // ---- tail2: hist/perm ----
    for (int i = t; i < 256; i += 1024) atomicAdd(&hist[min(cnt[i], 63)], 1);
    __syncthreads();
    if (t < 64) {
        int v = hist[t], s = v;
#pragma unroll
        for (int off = 1; off < 64; off <<= 1) {
            int u = __shfl_up(s, off, 64);
            if (lane >= off) s += u;
        }
        hist[t] = s - v;
    }
    __syncthreads();
    for (int i = t; i < 256; i += 1024) {
        int pos = atomicAdd(&hist[min(cnt[i], 63)], 1);
        perm[pos] = i;
    }
    __syncthreads();
    // ---- conv2 (LPN=4, QF=4; pairs from LDS lp) + bank stagger ----
    {
        int idx2 = t >> 2, h = t & 3;
        int nl = perm[idx2];
        int st = rstl[nl], cn = cnt[nl];
        float di = sdinv[nl], dii = di * di;
        const int2* pb = lp + st;
        int rotQ = (((t >> 2) & 15) - nl) & 15;   // quad stagger (16-chunk rot)
        int co[4];
#pragma unroll
        for (int i = 0; i < 4; ++i) co[i] = ((h * 4 + i + rotQ) & 15) * 4;
        float4 acc[4];
#pragma unroll
        for (int i = 0; i < 4; ++i) {
            float4 xv = *(const float4*)&shx[nl * 68 + co[i]];
            acc[i].x = fmaf(xv.x, dii, sbw[co[i] + 0]);
            acc[i].y = fmaf(xv.y, dii, sbw[co[i] + 1]);
            acc[i].z = fmaf(xv.z, dii, sbw[co[i] + 2]);
            acc[i].w = fmaf(xv.w, dii, sbw[co[i] + 3]);
        }
        int2 p0 = (cn > 0) ? pb[0] : make_int2(0, 0);
        int2 p1 = (cn > 1) ? pb[1] : make_int2(0, 0);
        for (int j = 0; j < cn; ++j) {
            int2 p2 = (j + 2 < cn) ? pb[j + 2] : make_int2(0, 0);
            float cfv = __int_as_float(p0.y);
            int   s   = p0.x;
#pragma unroll
            for (int i = 0; i < 4; ++i)
                acc[i] = f4fma(cfv, *(const float4*)&shx[s * 68 + co[i]], acc[i]);
            p0 = p1; p1 = p2;
        }
#pragma unroll
        for (int i = 0; i < 4; ++i) {
            acc[i].x = fmaxf(acc[i].x, 0.f); acc[i].y = fmaxf(acc[i].y, 0.f);
            acc[i].z = fmaxf(acc[i].z, 0.f); acc[i].w = fmaxf(acc[i].w, 0.f);
        }
        __syncthreads();
#pragma unroll
        for (int i = 0; i < 4; ++i)
            *(float4*)&shx[nl * 68 + co[i]] = acc[i];
    }
    __syncthreads();
    // ---- hp2 ----
    if (t < 512) {
        int wv8 = t >> 6, sub4 = (t >> 4) & 3;
        float4 w4 = wp2_4[lane16];
#pragma unroll
        for (int p = 0; p < 8; ++p) {
            int n2 = p * 32 + wv8 * 4 + sub4;
            float4 a = *(const float4*)&shx[n2 * 68 + lane16 * 4];
            float tt = a.x * w4.x + a.y * w4.y + a.z * w4.z + a.w * w4.w;
            tt += __shfl_xor(tt, 1, 64); tt += __shfl_xor(tt, 2, 64);
            tt += __shfl_xor(tt, 4, 64); tt += __shfl_xor(tt, 8, 64);
            if (lane16 == 0) shp[n2] = tt;
        }
    }
    __syncthreads();
    // ---- score2 ----
    if (t < 256) {
        int i = perm[t];
        int st = rstl[i], cn = cnt[i];
        float di = sdinv[i];
        const int2* pb = lp + st;
        float a = fmaf(shp[i], di * di, bp2[0]);
        int2 q0 = (cn > 0) ? pb[0] : make_int2(0, 0);
        int2 q1 = (cn > 1) ? pb[1] : make_int2(0, 0);
        for (int j = 0; j < cn; ++j) {
            int2 q2v = (j + 2 < cn) ? pb[j + 2] : make_int2(0, 0);
            a = fmaf(__int_as_float(q0.y), shp[q0.x], a);
            q0 = q1; q1 = q2v;
        }
        ssc[i] = a;
    }
    __syncthreads();
    // ---- rank2 (4 partials per node) ----
    {
        int part = t >> 8, i = t & 255;
        float si = ssc[i];
        int j0 = part * 64, rank = 0;
        for (int j = j0; j < j0 + 64; j += 4) {
            float4 sj = *(const float4*)&ssc[j];
            rank += (sj.x > si) || (sj.x == si && j     < i);
            rank += (sj.y > si) || (sj.y == si && j + 1 < i);
            rank += (sj.z > si) || (sj.z == si && j + 2 < i);
            rank += (sj.w > si) || (sj.w == si && j + 3 < i);
        }
        atomicAdd(&rnk[i], rank);
    }
    __syncthreads();
    // ---- readout2 + final out ----
    {
        float4 mx = make_float4(-3.402823466e38f, -3.402823466e38f, -3.402823466e38f, -3.402823466e38f);
        float4 sm = make_float4(0.f, 0.f, 0.f, 0.f);
        if (t < 512) {
            int wv8 = t >> 6, sub4 = (t >> 4) & 3;
#pragma unroll
            for (int p = 0; p < 8; ++p) {
                int n2 = p * 32 + wv8 * 4 + sub4;
                int r = rnk[n2];
                if (r < 128) {
                    float gt = tanhf(ssc[n2]);
                    float4 v = *(const float4*)&shx[n2 * 68 + lane16 * 4];
                    v.x *= gt; v.y *= gt; v.z *= gt; v.w *= gt;
                    mx.x = fmaxf(mx.x, v.x); mx.y = fmaxf(mx.y, v.y);
                    mx.z = fmaxf(mx.z, v.z); mx.w = fmaxf(mx.w, v.w);
                    sm.x += v.x; sm.y += v.y; sm.z += v.z; sm.w += v.w;
                }
            }
        }
        int grp = t >> 4;
        __syncthreads();
        if (t < 512) redx[grp * 16 + lane16] = mx;
        __syncthreads();
        float mr[4] = {0, 0, 0, 0};
        if (grp == 0) {
#pragma unroll
            for (int u = 1; u < 32; ++u) {
                float4 a = redx[u * 16 + lane16];
                mx.x = fmaxf(mx.x, a.x); mx.y = fmaxf(mx.y, a.y);
                mx.z = fmaxf(mx.z, a.z); mx.w = fmaxf(mx.w, a.w);
            }
            mr[0] = mx.x; mr[1] = mx.y; mr[2] = mx.z; mr[3] = mx.w;
        }
        __syncthreads();
        if (t < 512) redx[grp * 16 + lane16] = sm;
        __syncthreads();
        if (grp == 0) {
#pragma unroll
            for (int u = 1; u < 32; ++u) {
                float4 b = redx[u * 16 + lane16];
                sm.x += b.x; sm.y += b.y; sm.z += b.z; sm.w += b.w;
            }
            float invK = 1.f / 128.f;
            int c = lane16 * 4;
            float ar[4] = {sm.x * invK, sm.y * invK, sm.z * invK, sm.w * invK};
#pragma unroll
            for (int u = 0; u < 4; ++u) {
                out[g * 128 + c + u]      = 0.5f * (x1rs[c + u]      + mr[u]);
                out[g * 128 + 64 + c + u] = 0.5f * (x1rs[64 + c + u] + ar[u]);
            }
        }
    }
}

extern "C" void kernel_launch(void* const* d_in, const int* in_sizes, int n_in,
                              void* d_out, int out_size, void* d_ws, size_t ws_size,
                              hipStream_t stream) {
    const float* x    = (const float*)d_in[0];
    const float* eatt = (const float*)d_in[1];
    const float* W1   = (const float*)d_in[2];
    const float* b1   = (const float*)d_in[3];
    const float* Wp1  = (const float*)d_in[4];
    const float* bp1  = (const float*)d_in[5];
    const float* W2   = (const float*)d_in[6];
    const float* b2   = (const float*)d_in[7];
    const float* Wp2  = (const float*)d_in[8];
    const float* bp2  = (const float*)d_in[9];
    const int*   esrc = (const int*)d_in[10];
    const int*   edst = (const int*)d_in[11];
    float* out = (float*)d_out;

    int2* prs = (int2*)d_ws;                     // [NE] only workspace user

    mega_kernel<<<BG, 1024, 0, stream>>>(
        esrc, edst, eatt, prs, (const float4*)x,
        (const float4*)W1, (const float4*)b1, (const float4*)Wp1, bp1,
        (const float4*)W2, (const float4*)b2, (const float4*)Wp2, bp2,
        out);
}